// Round 1
// baseline (542.264 us; speedup 1.0000x reference)
//
#include <hip/hip_runtime.h>
#include <hip/hip_bf16.h>

#define B_ 16384
#define E_ 1024
#define H_ 8
#define D_ 128
#define BK 32
#define BM 64
#define PADK 40   // padded LDS row stride (elems): 80 B, 16B-aligned, breaks pow2 bank stride

typedef _Float16 f16;
typedef _Float16 f16x8 __attribute__((ext_vector_type(8)));
typedef float f32x4 __attribute__((ext_vector_type(4)));

// ---------------- f32 -> f16 conversion ----------------
__global__ __launch_bounds__(256) void cvt_kernel(const float4* __restrict__ src,
                                                  ushort4* __restrict__ dst, int n4) {
    int i = blockIdx.x * 256 + threadIdx.x;
    if (i >= n4) return;
    float4 v = src[i];
    union { ushort4 u; f16 h[4]; } o;
    o.h[0] = (f16)v.x; o.h[1] = (f16)v.y; o.h[2] = (f16)v.z; o.h[3] = (f16)v.w;
    dst[i] = o.u;
}

// ---------------- fused QKV projection + 2-key attention -> ctx ----------------
// grid: (B/BM, H). Block 256 threads = 4 waves, wave grid 2x2 over (64 rows x 128 head cols).
__global__ __launch_bounds__(256) void qkv_attn_kernel(
    const f16* __restrict__ Xi, const f16* __restrict__ Xs,
    const f16* __restrict__ Wq, const f16* __restrict__ Wk, const f16* __restrict__ Wv,
    const float* __restrict__ bq, const float* __restrict__ bk, const float* __restrict__ bv,
    f16* __restrict__ ctx)
{
    __shared__ f16 sAi[BM][PADK];
    __shared__ f16 sAs[BM][PADK];
    __shared__ f16 sW1[D_][PADK];
    __shared__ f16 sW2[D_][PADK];
    __shared__ float sdot[2][BM][2];
    __shared__ float sa0[BM], sa1[BM];

    const int tid  = threadIdx.x;
    const int lane = tid & 63;
    const int wave = tid >> 6;
    const int wr = wave >> 1, wc = wave & 1;
    const int l16 = lane & 15, lq = lane >> 4;

    const int row0 = blockIdx.x * BM;
    const int col0 = blockIdx.y * D_;   // head slice in E

    // staging assignment: A tiles: 64 rows x 4 chunks of 8; W slices: 128 rows x 4 chunks (2 per thread)
    const int srow  = tid >> 2;
    const int scol  = (tid & 3) * 8;
    const int wrow0 = tid >> 2;
    const int wrow1 = 64 + (tid >> 2);

    f32x4 zero4 = {0.f, 0.f, 0.f, 0.f};
    f32x4 accQ[2][4], accKi[2][4], accKs[2][4];
    #pragma unroll
    for (int i = 0; i < 2; i++)
        #pragma unroll
        for (int j = 0; j < 4; j++) { accQ[i][j] = zero4; accKi[i][j] = zero4; accKs[i][j] = zero4; }

    // ---- phase 1: Q = Xi@Wq_h^T, Kimg = Xi@Wk_h^T, Ksig = Xs@Wk_h^T ----
    for (int kk = 0; kk < E_; kk += BK) {
        uint4 vAi = *(const uint4*)&Xi[(size_t)(row0 + srow) * E_ + kk + scol];
        uint4 vAs = *(const uint4*)&Xs[(size_t)(row0 + srow) * E_ + kk + scol];
        uint4 vQ0 = *(const uint4*)&Wq[(size_t)(col0 + wrow0) * E_ + kk + scol];
        uint4 vQ1 = *(const uint4*)&Wq[(size_t)(col0 + wrow1) * E_ + kk + scol];
        uint4 vK0 = *(const uint4*)&Wk[(size_t)(col0 + wrow0) * E_ + kk + scol];
        uint4 vK1 = *(const uint4*)&Wk[(size_t)(col0 + wrow1) * E_ + kk + scol];
        __syncthreads();
        *(uint4*)&sAi[srow][scol]  = vAi;
        *(uint4*)&sAs[srow][scol]  = vAs;
        *(uint4*)&sW1[wrow0][scol] = vQ0;
        *(uint4*)&sW1[wrow1][scol] = vQ1;
        *(uint4*)&sW2[wrow0][scol] = vK0;
        *(uint4*)&sW2[wrow1][scol] = vK1;
        __syncthreads();

        f16x8 aI[2], aS[2], bQ[4], bK[4];
        #pragma unroll
        for (int fr = 0; fr < 2; fr++) {
            aI[fr] = *(const f16x8*)&sAi[wr * 32 + fr * 16 + l16][lq * 8];
            aS[fr] = *(const f16x8*)&sAs[wr * 32 + fr * 16 + l16][lq * 8];
        }
        #pragma unroll
        for (int fc = 0; fc < 4; fc++) {
            bQ[fc] = *(const f16x8*)&sW1[wc * 64 + fc * 16 + l16][lq * 8];
            bK[fc] = *(const f16x8*)&sW2[wc * 64 + fc * 16 + l16][lq * 8];
        }
        #pragma unroll
        for (int fr = 0; fr < 2; fr++)
            #pragma unroll
            for (int fc = 0; fc < 4; fc++) {
                accQ[fr][fc]  = __builtin_amdgcn_mfma_f32_16x16x32_f16(aI[fr], bQ[fc], accQ[fr][fc], 0, 0, 0);
                accKi[fr][fc] = __builtin_amdgcn_mfma_f32_16x16x32_f16(aI[fr], bK[fc], accKi[fr][fc], 0, 0, 0);
                accKs[fr][fc] = __builtin_amdgcn_mfma_f32_16x16x32_f16(aS[fr], bK[fc], accKs[fr][fc], 0, 0, 0);
            }
    }

    // biases (zero in practice but correct in general)
    #pragma unroll
    for (int fc = 0; fc < 4; fc++) {
        int col = col0 + wc * 64 + fc * 16 + l16;
        float bqv = bq[col], bkv = bk[col];
        #pragma unroll
        for (int fr = 0; fr < 2; fr++)
            #pragma unroll
            for (int e = 0; e < 4; e++) {
                accQ[fr][fc][e]  += bqv;
                accKi[fr][fc][e] += bkv;
                accKs[fr][fc][e] += bkv;
            }
    }

    // ---- scores: per-row dot(q, k) over this head's 128 cols ----
    // C layout: col = lane&15, row = (lane>>4)*4 + e  (within 16x16 frag)
    #pragma unroll
    for (int fr = 0; fr < 2; fr++)
        #pragma unroll
        for (int e = 0; e < 4; e++) {
            float d0 = 0.f, d1 = 0.f;
            #pragma unroll
            for (int fc = 0; fc < 4; fc++) {
                d0 += accQ[fr][fc][e] * accKi[fr][fc][e];
                d1 += accQ[fr][fc][e] * accKs[fr][fc][e];
            }
            #pragma unroll
            for (int m = 1; m < 16; m <<= 1) {
                d0 += __shfl_xor(d0, m, 64);
                d1 += __shfl_xor(d1, m, 64);
            }
            if (l16 == 0) {
                int row = wr * 32 + fr * 16 + lq * 4 + e;
                sdot[0][row][wc] = d0;
                sdot[1][row][wc] = d1;
            }
        }
    __syncthreads();
    if (tid < BM) {
        const float scale = 0.088388347648318447f;  // 1/sqrt(128)
        float s0 = (sdot[0][tid][0] + sdot[0][tid][1]) * scale;
        float s1 = (sdot[1][tid][0] + sdot[1][tid][1]) * scale;
        float a0 = 1.0f / (1.0f + expf(s1 - s0));
        sa0[tid] = a0;
        sa1[tid] = 1.0f - a0;
    }
    __syncthreads();
    const float a0r = sa0[srow];
    const float a1r = sa1[srow];

    // ---- phase 2: ctx_h = (a0*xi + a1*xs) @ Wv_h^T  (linearity of softmax-mix) ----
    f32x4 accC[2][4];
    #pragma unroll
    for (int i = 0; i < 2; i++)
        #pragma unroll
        for (int j = 0; j < 4; j++) accC[i][j] = zero4;

    for (int kk = 0; kk < E_; kk += BK) {
        union { uint4 u; f16 h[8]; } xi, xs, xm;
        xi.u = *(const uint4*)&Xi[(size_t)(row0 + srow) * E_ + kk + scol];
        xs.u = *(const uint4*)&Xs[(size_t)(row0 + srow) * E_ + kk + scol];
        uint4 vV0 = *(const uint4*)&Wv[(size_t)(col0 + wrow0) * E_ + kk + scol];
        uint4 vV1 = *(const uint4*)&Wv[(size_t)(col0 + wrow1) * E_ + kk + scol];
        #pragma unroll
        for (int j = 0; j < 8; j++)
            xm.h[j] = (f16)(a0r * (float)xi.h[j] + a1r * (float)xs.h[j]);
        __syncthreads();
        *(uint4*)&sAi[srow][scol]  = xm.u;
        *(uint4*)&sW1[wrow0][scol] = vV0;
        *(uint4*)&sW1[wrow1][scol] = vV1;
        __syncthreads();

        f16x8 aM[2], bV[4];
        #pragma unroll
        for (int fr = 0; fr < 2; fr++)
            aM[fr] = *(const f16x8*)&sAi[wr * 32 + fr * 16 + l16][lq * 8];
        #pragma unroll
        for (int fc = 0; fc < 4; fc++)
            bV[fc] = *(const f16x8*)&sW1[wc * 64 + fc * 16 + l16][lq * 8];
        #pragma unroll
        for (int fr = 0; fr < 2; fr++)
            #pragma unroll
            for (int fc = 0; fc < 4; fc++)
                accC[fr][fc] = __builtin_amdgcn_mfma_f32_16x16x32_f16(aM[fr], bV[fc], accC[fr][fc], 0, 0, 0);
    }

    #pragma unroll
    for (int fc = 0; fc < 4; fc++) {
        int col = col0 + wc * 64 + fc * 16 + l16;
        float bvv = bv[col];
        #pragma unroll
        for (int fr = 0; fr < 2; fr++)
            #pragma unroll
            for (int e = 0; e < 4; e++) {
                int row = row0 + wr * 32 + fr * 16 + lq * 4 + e;
                ctx[(size_t)row * E_ + col] = (f16)(accC[fr][fc][e] + bvv);
            }
    }
}

// ---------------- out projection: ctx @ Wo^T + bo + residual -> f32 ----------------
// grid (B/128, E/128), 256 threads, 4 waves each 64x64 (4x4 frags)
__global__ __launch_bounds__(256) void out_proj_kernel(
    const f16* __restrict__ A, const f16* __restrict__ Wo, const float* __restrict__ bo,
    const float* __restrict__ resid, float* __restrict__ out)
{
    __shared__ f16 sA[128][PADK];
    __shared__ f16 sB[128][PADK];
    const int tid  = threadIdx.x;
    const int lane = tid & 63;
    const int wave = tid >> 6;
    const int wr = wave >> 1, wc = wave & 1;
    const int l16 = lane & 15, lq = lane >> 4;
    const int row0 = blockIdx.x * 128;
    const int col0 = blockIdx.y * 128;
    const int crow0 = tid >> 2, crow1 = 64 + (tid >> 2);
    const int scol  = (tid & 3) * 8;

    f32x4 zero4 = {0.f, 0.f, 0.f, 0.f};
    f32x4 acc[4][4];
    #pragma unroll
    for (int i = 0; i < 4; i++)
        #pragma unroll
        for (int j = 0; j < 4; j++) acc[i][j] = zero4;

    for (int kk = 0; kk < E_; kk += BK) {
        uint4 a0v = *(const uint4*)&A[(size_t)(row0 + crow0) * E_ + kk + scol];
        uint4 a1v = *(const uint4*)&A[(size_t)(row0 + crow1) * E_ + kk + scol];
        uint4 b0v = *(const uint4*)&Wo[(size_t)(col0 + crow0) * E_ + kk + scol];
        uint4 b1v = *(const uint4*)&Wo[(size_t)(col0 + crow1) * E_ + kk + scol];
        __syncthreads();
        *(uint4*)&sA[crow0][scol] = a0v;
        *(uint4*)&sA[crow1][scol] = a1v;
        *(uint4*)&sB[crow0][scol] = b0v;
        *(uint4*)&sB[crow1][scol] = b1v;
        __syncthreads();

        f16x8 aF[4], bF[4];
        #pragma unroll
        for (int f = 0; f < 4; f++) {
            aF[f] = *(const f16x8*)&sA[wr * 64 + f * 16 + l16][lq * 8];
            bF[f] = *(const f16x8*)&sB[wc * 64 + f * 16 + l16][lq * 8];
        }
        #pragma unroll
        for (int fr = 0; fr < 4; fr++)
            #pragma unroll
            for (int fc = 0; fc < 4; fc++)
                acc[fr][fc] = __builtin_amdgcn_mfma_f32_16x16x32_f16(aF[fr], bF[fc], acc[fr][fc], 0, 0, 0);
    }

    #pragma unroll
    for (int fc = 0; fc < 4; fc++) {
        int col = col0 + wc * 64 + fc * 16 + l16;
        float bov = bo[col];
        #pragma unroll
        for (int fr = 0; fr < 4; fr++)
            #pragma unroll
            for (int e = 0; e < 4; e++) {
                int row = row0 + wr * 64 + fr * 16 + lq * 4 + e;
                out[(size_t)row * E_ + col] = acc[fr][fc][e] + bov + resid[(size_t)row * E_ + col];
            }
    }
}

// ---------------- in-place LayerNorm over E=1024 ----------------
__global__ __launch_bounds__(256) void ln_kernel(
    float* __restrict__ x, const float* __restrict__ gamma,
    const float* __restrict__ beta, float* __restrict__ out)
{
    const int row = blockIdx.x;
    const int tid = threadIdx.x;
    const float4* xr = (const float4*)(x + (size_t)row * E_);
    float4 v = xr[tid];
    float s  = v.x + v.y + v.z + v.w;
    float s2 = v.x * v.x + v.y * v.y + v.z * v.z + v.w * v.w;
    #pragma unroll
    for (int m = 1; m < 64; m <<= 1) {
        s  += __shfl_xor(s, m, 64);
        s2 += __shfl_xor(s2, m, 64);
    }
    __shared__ float red[8];
    int wv = tid >> 6, ln = tid & 63;
    if (ln == 0) { red[wv] = s; red[4 + wv] = s2; }
    __syncthreads();
    s  = red[0] + red[1] + red[2] + red[3];
    s2 = red[4] + red[5] + red[6] + red[7];
    float mu  = s * (1.0f / E_);
    float var = s2 * (1.0f / E_) - mu * mu;
    float r   = rsqrtf(var + 1e-5f);
    float4 g  = ((const float4*)gamma)[tid];
    float4 bb = ((const float4*)beta)[tid];
    float4 o;
    o.x = (v.x - mu) * r * g.x + bb.x;
    o.y = (v.y - mu) * r * g.y + bb.y;
    o.z = (v.z - mu) * r * g.z + bb.z;
    o.w = (v.w - mu) * r * g.w + bb.w;
    ((float4*)(out + (size_t)row * E_))[tid] = o;
}

extern "C" void kernel_launch(void* const* d_in, const int* in_sizes, int n_in,
                              void* d_out, int out_size, void* d_ws, size_t ws_size,
                              hipStream_t stream)
{
    (void)in_sizes; (void)n_in; (void)out_size; (void)ws_size;
    const float* image  = (const float*)d_in[0];
    const float* signal = (const float*)d_in[1];
    const float* Wq = (const float*)d_in[2];
    const float* Wk = (const float*)d_in[3];
    const float* Wv = (const float*)d_in[4];
    const float* bq = (const float*)d_in[5];
    const float* bk = (const float*)d_in[6];
    const float* bv = (const float*)d_in[7];
    const float* Wo = (const float*)d_in[8];
    const float* bo = (const float*)d_in[9];
    const float* gamma = (const float*)d_in[10];
    const float* beta  = (const float*)d_in[11];
    float* out = (float*)d_out;

    char* ws = (char*)d_ws;
    f16* Xi16 = (f16*)(ws);                            // 32 MB
    f16* Xs16 = (f16*)(ws + 32ull * 1024 * 1024);      // 32 MB
    f16* Wq16 = (f16*)(ws + 64ull * 1024 * 1024);      // 2 MB
    f16* Wk16 = (f16*)(ws + 66ull * 1024 * 1024);      // 2 MB
    f16* Wv16 = (f16*)(ws + 68ull * 1024 * 1024);      // 2 MB
    f16* Wo16 = (f16*)(ws + 70ull * 1024 * 1024);      // 2 MB
    f16* ctx  = (f16*)(ws + 72ull * 1024 * 1024);      // 32 MB  (total 104 MB)

    const int nBE4 = B_ * E_ / 4;   // 4194304
    const int nEE4 = E_ * E_ / 4;   // 262144
    cvt_kernel<<<nBE4 / 256, 256, 0, stream>>>((const float4*)image,  (ushort4*)Xi16, nBE4);
    cvt_kernel<<<nBE4 / 256, 256, 0, stream>>>((const float4*)signal, (ushort4*)Xs16, nBE4);
    cvt_kernel<<<nEE4 / 256, 256, 0, stream>>>((const float4*)Wq, (ushort4*)Wq16, nEE4);
    cvt_kernel<<<nEE4 / 256, 256, 0, stream>>>((const float4*)Wk, (ushort4*)Wk16, nEE4);
    cvt_kernel<<<nEE4 / 256, 256, 0, stream>>>((const float4*)Wv, (ushort4*)Wv16, nEE4);
    cvt_kernel<<<nEE4 / 256, 256, 0, stream>>>((const float4*)Wo, (ushort4*)Wo16, nEE4);

    dim3 g2(B_ / BM, H_);
    qkv_attn_kernel<<<g2, 256, 0, stream>>>(Xi16, Xs16, Wq16, Wk16, Wv16, bq, bk, bv, ctx);

    dim3 g4(B_ / 128, E_ / 128);
    out_proj_kernel<<<g4, 256, 0, stream>>>(ctx, Wo16, bo, image, out);

    ln_kernel<<<B_, 256, 0, stream>>>(out, gamma, beta, out);
}